// Round 1
// 522.871 us; speedup vs baseline: 1.0343x; 1.0343x over previous
//
#include <hip/hip_runtime.h>
#include <hip/hip_bf16.h>
#include <math.h>

constexpr int IN_C = 1024;
constexpr int HEADS = 4;
constexpr int F1 = 256;
constexpr int OUT_C = 64;
constexpr float NEG = 0.2f;

using bf16x8 = __attribute__((ext_vector_type(8))) short;
using f32x4 = __attribute__((ext_vector_type(4))) float;

__device__ __forceinline__ float leaky(float x) { return x > 0.f ? x : NEG * x; }

__device__ __forceinline__ unsigned short bf16bits(float v) {
  __hip_bfloat16 b = __float2bfloat16(v);
  return *reinterpret_cast<unsigned short*>(&b);
}
__device__ __forceinline__ float bf2f(unsigned short u) {
  union { unsigned u; float f; } c; c.u = (unsigned)u << 16; return c.f;
}

#define GLD_LDS16(g, l)                                                        \
  __builtin_amdgcn_global_load_lds(                                            \
      (const __attribute__((address_space(1))) void*)(g),                      \
      (__attribute__((address_space(3))) void*)(l), 16, 0, 0)

// ---------------- fused prep: cvt W1 -> bf16, cvt W2 -> bf16, degree count ----------------
// block-range dispatch: [0,1024) = W1, [1024,1088) = W2, rest = degree.
constexpr int NB_W1 = (F1 * IN_C) / 256;    // 1024 (exact)
constexpr int NB_W2 = (OUT_C * F1) / 256;   // 64 (exact)

__global__ __launch_bounds__(256) void prep_kernel(const float* __restrict__ W1,
                                                   unsigned short* __restrict__ W1b,
                                                   const float* __restrict__ W2,
                                                   unsigned short* __restrict__ W2b,
                                                   const int* __restrict__ ei, int E, int N,
                                                   int* __restrict__ deg) {
  int b = blockIdx.x;
  if (b < NB_W1) {
    int i = b * 256 + threadIdx.x;
    W1b[i] = bf16bits(W1[i]);
  } else if (b < NB_W1 + NB_W2) {
    int i = (b - NB_W1) * 256 + threadIdx.x;
    W2b[i] = bf16bits(W2[i]);
  } else {
    int e = (b - NB_W1 - NB_W2) * 256 + threadIdx.x;
    if (e < E + N) {
      int dst = (e < E) ? ei[E + e] : (e - E);
      atomicAdd(&deg[dst], 1);
    }
  }
}

// ------- GEMM1: Hb[M,256] = X*W1^T (bf16 MFMA) + fused alpha dot-products ---------
constexpr int LDTA = 72;

__global__ __launch_bounds__(256, 2) void gemm1_mfma(const float* __restrict__ X,
                                                     const unsigned short* __restrict__ Wb,
                                                     unsigned short* __restrict__ Hb,
                                                     const float* __restrict__ a_src,
                                                     const float* __restrict__ a_dst,
                                                     float* __restrict__ as_out,
                                                     float* __restrict__ ad_out, int M) {
  __shared__ unsigned short As[64 * LDTA];
  __shared__ unsigned short Bs[256 * 64];
  const int tid = threadIdx.x;
  const int wave = tid >> 6;
  const int lane = tid & 63;
  const int m15 = lane & 15;
  const int q = lane >> 4;
  const int bm = blockIdx.x * 64;

  f32x4 acc[4][4];
#pragma unroll
  for (int i = 0; i < 4; ++i)
#pragma unroll
    for (int j = 0; j < 4; ++j) acc[i][j] = (f32x4){0.f, 0.f, 0.f, 0.f};

  const int ar = tid >> 2;
  const int acg = (tid & 3) * 16;
  const int agr = (bm + ar < M) ? (bm + ar) : (M - 1);
  const float* aptr = X + (size_t)agr * IN_C + acg;

  for (int kt = 0; kt < IN_C; kt += 64) {
    // A global loads first (HBM, longest latency)
    float4 a0 = *(const float4*)(aptr + kt + 0);
    float4 a1 = *(const float4*)(aptr + kt + 4);
    float4 a2 = *(const float4*)(aptr + kt + 8);
    float4 a3 = *(const float4*)(aptr + kt + 12);
    // B staging (L2-resident after first touch)
#pragma unroll
    for (int p = 0; p < 8; ++p) {
      int s = p * 256 + tid;
      int r = s >> 3;
      int cb = s & 7;
      const unsigned short* g = Wb + (size_t)r * IN_C + kt + ((cb ^ (r & 7)) << 3);
      GLD_LDS16(g, &Bs[(p * 256 + wave * 64) * 8]);
    }
    union { uint4 u4[2]; __hip_bfloat162 h[8]; } pk;
    pk.h[0] = __float22bfloat162_rn(make_float2(a0.x, a0.y));
    pk.h[1] = __float22bfloat162_rn(make_float2(a0.z, a0.w));
    pk.h[2] = __float22bfloat162_rn(make_float2(a1.x, a1.y));
    pk.h[3] = __float22bfloat162_rn(make_float2(a1.z, a1.w));
    pk.h[4] = __float22bfloat162_rn(make_float2(a2.x, a2.y));
    pk.h[5] = __float22bfloat162_rn(make_float2(a2.z, a2.w));
    pk.h[6] = __float22bfloat162_rn(make_float2(a3.x, a3.y));
    pk.h[7] = __float22bfloat162_rn(make_float2(a3.z, a3.w));
    *(uint4*)&As[ar * LDTA + acg] = pk.u4[0];
    *(uint4*)&As[ar * LDTA + acg + 8] = pk.u4[1];
    __syncthreads();

#pragma unroll
    for (int k0 = 0; k0 < 64; k0 += 32) {
      bf16x8 af[4], bfr[4];
#pragma unroll
      for (int i = 0; i < 4; ++i)
        af[i] = *(const bf16x8*)&As[(i * 16 + m15) * LDTA + k0 + q * 8];
#pragma unroll
      for (int j = 0; j < 4; ++j) {
        int rb = wave * 64 + j * 16 + m15;
        int cbp = ((k0 >> 3) + q) ^ (rb & 7);
        bfr[j] = *(const bf16x8*)&Bs[rb * 64 + cbp * 8];
      }
#pragma unroll
      for (int i = 0; i < 4; ++i)
#pragma unroll
        for (int j = 0; j < 4; ++j)
          acc[i][j] = __builtin_amdgcn_mfma_f32_16x16x32_bf16(af[i], bfr[j], acc[i][j], 0, 0, 0);
    }
    __syncthreads();
  }
  float asf[4], adf[4];
#pragma unroll
  for (int j = 0; j < 4; ++j) {
    asf[j] = a_src[wave * 64 + j * 16 + m15];
    adf[j] = a_dst[wave * 64 + j * 16 + m15];
  }
#pragma unroll
  for (int i = 0; i < 4; ++i) {
#pragma unroll
    for (int r = 0; r < 4; ++r) {
      int row = bm + i * 16 + q * 4 + r;
      if (row < M) {
#pragma unroll
        for (int j = 0; j < 4; ++j)
          Hb[(size_t)row * F1 + wave * 64 + j * 16 + m15] = bf16bits(acc[i][j][r]);
      }
      float s = acc[i][0][r] * asf[0] + acc[i][1][r] * asf[1] +
                acc[i][2][r] * asf[2] + acc[i][3][r] * asf[3];
      float d = acc[i][0][r] * adf[0] + acc[i][1][r] * adf[1] +
                acc[i][2][r] * adf[2] + acc[i][3][r] * adf[3];
#pragma unroll
      for (int o = 1; o < 16; o <<= 1) {
        s += __shfl_xor(s, o, 64);
        d += __shfl_xor(d, o, 64);
      }
      if (m15 == 0 && row < M) {
        as_out[row * HEADS + wave] = s;
        ad_out[row * HEADS + wave] = d;
      }
    }
  }
}

// ------- GEMM2: H2[M,64] = Y(bf16)*W2^T (bf16 MFMA) + fused alpha -----------------
__global__ __launch_bounds__(256, 4) void gemm2_mfma(const unsigned short* __restrict__ Y,
                                                     const unsigned short* __restrict__ W2b,
                                                     float* __restrict__ H2,
                                                     const float* __restrict__ a_src,
                                                     const float* __restrict__ a_dst,
                                                     float* __restrict__ as_out,
                                                     float* __restrict__ ad_out, int M) {
  __shared__ unsigned short As[64 * 64];
  __shared__ unsigned short Bs[64 * 64];
  const int tid = threadIdx.x;
  const int wave = tid >> 6;
  const int lane = tid & 63;
  const int m15 = lane & 15;
  const int q = lane >> 4;
  const int bm = blockIdx.x * 64;

  f32x4 acc[4];
#pragma unroll
  for (int j = 0; j < 4; ++j) acc[j] = (f32x4){0.f, 0.f, 0.f, 0.f};

  for (int kt = 0; kt < F1; kt += 64) {
#pragma unroll
    for (int p = 0; p < 2; ++p) {
      int s = p * 256 + tid;
      int r = s >> 3;
      int cb = s & 7;
      int colo = (cb ^ (r & 7)) << 3;
      int gr = (bm + r < M) ? (bm + r) : (M - 1);
      GLD_LDS16(Y + (size_t)gr * F1 + kt + colo, &As[(p * 256 + wave * 64) * 8]);
      GLD_LDS16(W2b + (size_t)r * F1 + kt + colo, &Bs[(p * 256 + wave * 64) * 8]);
    }
    __syncthreads();
#pragma unroll
    for (int k0 = 0; k0 < 64; k0 += 32) {
      int ra = wave * 16 + m15;
      bf16x8 af = *(const bf16x8*)&As[ra * 64 + ((((k0 >> 3) + q) ^ (ra & 7)) << 3)];
      bf16x8 bfr[4];
#pragma unroll
      for (int j = 0; j < 4; ++j) {
        int rb = j * 16 + m15;
        bfr[j] = *(const bf16x8*)&Bs[rb * 64 + ((((k0 >> 3) + q) ^ (rb & 7)) << 3)];
      }
#pragma unroll
      for (int j = 0; j < 4; ++j)
        acc[j] = __builtin_amdgcn_mfma_f32_16x16x32_bf16(af, bfr[j], acc[j], 0, 0, 0);
    }
    __syncthreads();
  }
  float asf[4], adf[4];
#pragma unroll
  for (int j = 0; j < 4; ++j) {
    asf[j] = a_src[j * 16 + m15];
    adf[j] = a_dst[j * 16 + m15];
  }
#pragma unroll
  for (int r = 0; r < 4; ++r) {
    int row = bm + wave * 16 + q * 4 + r;
    if (row < M) {
#pragma unroll
      for (int j = 0; j < 4; ++j) H2[(size_t)row * OUT_C + j * 16 + m15] = acc[j][r];
    }
    float s = acc[0][r] * asf[0] + acc[1][r] * asf[1] + acc[2][r] * asf[2] + acc[3][r] * asf[3];
    float d = acc[0][r] * adf[0] + acc[1][r] * adf[1] + acc[2][r] * adf[2] + acc[3][r] * adf[3];
#pragma unroll
    for (int o = 1; o < 16; o <<= 1) {
      s += __shfl_xor(s, o, 64);
      d += __shfl_xor(d, o, 64);
    }
    if (m15 == 0 && row < M) {
      as_out[row] = s;
      ad_out[row] = d;
    }
  }
}

// ---------------- CSR build ----------------
__global__ __launch_bounds__(256) void scan_block_sums(const int* __restrict__ deg,
                                                       int* __restrict__ part, int n) {
  __shared__ int sm[256];
  int t = threadIdx.x;
  int i = blockIdx.x * 256 + t;
  sm[t] = (i < n) ? deg[i] : 0;
  __syncthreads();
  for (int off = 128; off > 0; off >>= 1) {
    if (t < off) sm[t] += sm[t + off];
    __syncthreads();
  }
  if (t == 0) part[blockIdx.x] = sm[0];
}

// final scan: each block computes its own exclusive base from raw block sums
// (P <= 256 partials -> one wave-butterfly + LDS combine; removes scan_partials launch)
__global__ __launch_bounds__(256) void scan_final2(const int* __restrict__ deg,
                                                   const int* __restrict__ part,
                                                   int* __restrict__ row_ptr, int n) {
  __shared__ int sm[256];
  __shared__ int wsum[4];
  int t = threadIdx.x;
  int i = blockIdx.x * 256 + t;
  sm[t] = (i < n) ? deg[i] : 0;
  // exclusive base = sum of part[0..blockIdx.x-1]
  int pv = (t < blockIdx.x) ? part[t] : 0;
#pragma unroll
  for (int o = 1; o < 64; o <<= 1) pv += __shfl_xor(pv, o, 64);
  if ((t & 63) == 0) wsum[t >> 6] = pv;
  __syncthreads();
  for (int off = 1; off < 256; off <<= 1) {
    int u = (t >= off) ? sm[t - off] : 0;
    __syncthreads();
    sm[t] += u;
    __syncthreads();
  }
  int base = wsum[0] + wsum[1] + wsum[2] + wsum[3];
  if (i < n) row_ptr[i + 1] = base + sm[t];
  if (i == 0) row_ptr[0] = 0;
}

__global__ void scatter_kernel(const int* __restrict__ ei, int E, int N,
                               const int* __restrict__ row_ptr, int* __restrict__ fill,
                               int* __restrict__ col) {
  int e = blockIdx.x * blockDim.x + threadIdx.x;
  if (e >= E + N) return;
  int src, dst;
  if (e < E) { src = ei[e]; dst = ei[E + e]; }
  else       { src = e - E; dst = e - E; }
  int pos = row_ptr[dst] + atomicAdd(&fill[dst], 1);
  col[pos] = src;
}

// ------- layer-1 aggregate: wave/dst, FOUR edges in flight per 32-lane half --------
// lane&31 = channel-group (8 ch, uint4), lane>>5 = edge parity; head = (lane&31)>>3.
__global__ __launch_bounds__(256) void agg1_kernel(const unsigned short* __restrict__ hb,
                                                   const float* __restrict__ as,
                                                   const float* __restrict__ ad,
                                                   const int* __restrict__ row_ptr,
                                                   const int* __restrict__ col,
                                                   const float* __restrict__ bias,
                                                   unsigned short* __restrict__ yb, int N) {
  int dst = (blockIdx.x * blockDim.x + threadIdx.x) >> 6;
  int lane = threadIdx.x & 63;
  if (dst >= N) return;
  const int s0 = row_ptr[dst], s1 = row_ptr[dst + 1];
  const int par = lane >> 5;
  const int cg = lane & 31;
  const int hh = cg >> 3;
  const float adl = ad[dst * 4 + hh];
  float acc[8];
#pragma unroll
  for (int k = 0; k < 8; ++k) acc[k] = 0.f;
  float den = 0.f;

  int i = s0 + par;
  for (; i + 6 < s1; i += 8) {  // 4 edges per parity per iter -> 8 rows in flight
    int sA = col[i], sB = col[i + 2], sC = col[i + 4], sD = col[i + 6];
    float wA = __expf(leaky(as[sA * 4 + hh] + adl));
    float wB = __expf(leaky(as[sB * 4 + hh] + adl));
    float wC = __expf(leaky(as[sC * 4 + hh] + adl));
    float wD = __expf(leaky(as[sD * 4 + hh] + adl));
    uint4 hA = *(const uint4*)(hb + (size_t)sA * F1 + cg * 8);
    uint4 hB = *(const uint4*)(hb + (size_t)sB * F1 + cg * 8);
    uint4 hC = *(const uint4*)(hb + (size_t)sC * F1 + cg * 8);
    uint4 hD = *(const uint4*)(hb + (size_t)sD * F1 + cg * 8);
    den += (wA + wB) + (wC + wD);
    const unsigned short* pa = (const unsigned short*)&hA;
    const unsigned short* pb = (const unsigned short*)&hB;
    const unsigned short* pc = (const unsigned short*)&hC;
    const unsigned short* pd = (const unsigned short*)&hD;
#pragma unroll
    for (int k = 0; k < 8; ++k) {
      acc[k] = fmaf(wA, bf2f(pa[k]), acc[k]);
      acc[k] = fmaf(wB, bf2f(pb[k]), acc[k]);
      acc[k] = fmaf(wC, bf2f(pc[k]), acc[k]);
      acc[k] = fmaf(wD, bf2f(pd[k]), acc[k]);
    }
  }
  for (; i + 2 < s1; i += 4) {  // 2 edges per parity
    int sA = col[i], sB = col[i + 2];
    float wA = __expf(leaky(as[sA * 4 + hh] + adl));
    float wB = __expf(leaky(as[sB * 4 + hh] + adl));
    uint4 hA = *(const uint4*)(hb + (size_t)sA * F1 + cg * 8);
    uint4 hB = *(const uint4*)(hb + (size_t)sB * F1 + cg * 8);
    den += wA + wB;
    const unsigned short* pa = (const unsigned short*)&hA;
    const unsigned short* pb = (const unsigned short*)&hB;
#pragma unroll
    for (int k = 0; k < 8; ++k) {
      acc[k] = fmaf(wA, bf2f(pa[k]), acc[k]);
      acc[k] = fmaf(wB, bf2f(pb[k]), acc[k]);
    }
  }
  for (; i < s1; i += 2) {
    int s = col[i];
    float w = __expf(leaky(as[s * 4 + hh] + adl));
    uint4 hv = *(const uint4*)(hb + (size_t)s * F1 + cg * 8);
    den += w;
    const unsigned short* p = (const unsigned short*)&hv;
#pragma unroll
    for (int k = 0; k < 8; ++k) acc[k] = fmaf(w, bf2f(p[k]), acc[k]);
  }
  // combine the two parities
  den += __shfl_xor(den, 32, 64);
#pragma unroll
  for (int k = 0; k < 8; ++k) acc[k] += __shfl_xor(acc[k], 32, 64);

  if (par == 0) {
    const float iv = 1.f / den;
    float4 b0 = *(const float4*)(bias + cg * 8);
    float4 b1 = *(const float4*)(bias + cg * 8 + 4);
    float bv[8] = {b0.x, b0.y, b0.z, b0.w, b1.x, b1.y, b1.z, b1.w};
    ushort4 o[2];
    unsigned short* po = (unsigned short*)o;
#pragma unroll
    for (int k = 0; k < 8; ++k) {
      float v = acc[k] * iv + bv[k];
      v = v > 0.f ? v : (__expf(v) - 1.f);
      po[k] = bf16bits(v);
    }
    *(uint4*)(yb + (size_t)dst * F1 + cg * 8) = *(uint4*)o;
  }
}

// ------- layer-2 aggregate: wave/dst, FOUR edges in flight per half ----------------
__global__ __launch_bounds__(256) void agg2_kernel(const float* __restrict__ h,
                                                   const float* __restrict__ as,
                                                   const float* __restrict__ ad,
                                                   const int* __restrict__ row_ptr,
                                                   const int* __restrict__ col,
                                                   const float* __restrict__ bias,
                                                   float* __restrict__ out, int N) {
  int dst = (blockIdx.x * blockDim.x + threadIdx.x) >> 6;
  int lane = threadIdx.x & 63;
  if (dst >= N) return;
  const int s0 = row_ptr[dst], s1 = row_ptr[dst + 1];
  const int par = lane >> 5;
  const int cg = lane & 31;
  const float adl = ad[dst];
  float a0 = 0.f, a1 = 0.f, den = 0.f;

  int i = s0 + par;
  for (; i + 6 < s1; i += 8) {
    int sA = col[i], sB = col[i + 2], sC = col[i + 4], sD = col[i + 6];
    float wA = __expf(leaky(as[sA] + adl));
    float wB = __expf(leaky(as[sB] + adl));
    float wC = __expf(leaky(as[sC] + adl));
    float wD = __expf(leaky(as[sD] + adl));
    float2 hA = *(const float2*)(h + (size_t)sA * OUT_C + cg * 2);
    float2 hB = *(const float2*)(h + (size_t)sB * OUT_C + cg * 2);
    float2 hC = *(const float2*)(h + (size_t)sC * OUT_C + cg * 2);
    float2 hD = *(const float2*)(h + (size_t)sD * OUT_C + cg * 2);
    den += (wA + wB) + (wC + wD);
    a0 = fmaf(wA, hA.x, a0); a1 = fmaf(wA, hA.y, a1);
    a0 = fmaf(wB, hB.x, a0); a1 = fmaf(wB, hB.y, a1);
    a0 = fmaf(wC, hC.x, a0); a1 = fmaf(wC, hC.y, a1);
    a0 = fmaf(wD, hD.x, a0); a1 = fmaf(wD, hD.y, a1);
  }
  for (; i + 2 < s1; i += 4) {
    int sA = col[i], sB = col[i + 2];
    float wA = __expf(leaky(as[sA] + adl));
    float wB = __expf(leaky(as[sB] + adl));
    float2 hA = *(const float2*)(h + (size_t)sA * OUT_C + cg * 2);
    float2 hB = *(const float2*)(h + (size_t)sB * OUT_C + cg * 2);
    den += wA + wB;
    a0 = fmaf(wA, hA.x, a0); a1 = fmaf(wA, hA.y, a1);
    a0 = fmaf(wB, hB.x, a0); a1 = fmaf(wB, hB.y, a1);
  }
  for (; i < s1; i += 2) {
    int s = col[i];
    float w = __expf(leaky(as[s] + adl));
    float2 hv = *(const float2*)(h + (size_t)s * OUT_C + cg * 2);
    den += w;
    a0 = fmaf(w, hv.x, a0); a1 = fmaf(w, hv.y, a1);
  }
  den += __shfl_xor(den, 32, 64);
  a0 += __shfl_xor(a0, 32, 64);
  a1 += __shfl_xor(a1, 32, 64);
  if (par == 0) {
    const float iv = 1.f / den;
    float2 bv = *(const float2*)(bias + cg * 2);
    float2 o = make_float2(a0 * iv + bv.x, a1 * iv + bv.y);
    *(float2*)(out + (size_t)dst * OUT_C + cg * 2) = o;
  }
}

extern "C" void kernel_launch(void* const* d_in, const int* in_sizes, int n_in,
                              void* d_out, int out_size, void* d_ws, size_t ws_size,
                              hipStream_t stream) {
  const float* x      = (const float*)d_in[0];
  const int*   ei     = (const int*)d_in[1];
  const float* W1     = (const float*)d_in[2];
  const float* a_src1 = (const float*)d_in[3];
  const float* a_dst1 = (const float*)d_in[4];
  const float* b1     = (const float*)d_in[5];
  const float* W2     = (const float*)d_in[6];
  const float* a_src2 = (const float*)d_in[7];
  const float* a_dst2 = (const float*)d_in[8];
  const float* b2     = (const float*)d_in[9];
  float* out = (float*)d_out;

  const int N = in_sizes[0] / IN_C;
  const int E = in_sizes[1] / 2;
  const int ET = E + N;

  char* ws = (char*)d_ws;
  size_t off = 0;
  auto alloc = [&](size_t bytes) -> void* {
    void* p = ws + off;
    off = (off + bytes + 255) & ~(size_t)255;
    return p;
  };
  unsigned short* h1b = (unsigned short*)alloc((size_t)N * F1 * 2);
  unsigned short* y1b = (unsigned short*)alloc((size_t)N * F1 * 2);
  float* h2      = (float*)alloc((size_t)N * OUT_C * 4);
  float* as1     = (float*)alloc((size_t)N * HEADS * 4);
  float* ad1     = (float*)alloc((size_t)N * HEADS * 4);
  float* as2     = (float*)alloc((size_t)N * 4);
  float* ad2     = (float*)alloc((size_t)N * 4);
  int*   deg     = (int*)alloc((size_t)N * 2 * 4);  // deg + fill, contiguous -> one memset
  int*   fill    = deg + N;
  int*   row_ptr = (int*)alloc((size_t)(N + 1) * 4);
  int*   col     = (int*)alloc((size_t)ET * 4);
  int*   part    = (int*)alloc(1024 * 4);
  unsigned short* W1b = (unsigned short*)alloc((size_t)F1 * IN_C * 2);
  unsigned short* W2b = (unsigned short*)alloc((size_t)OUT_C * F1 * 2);
  (void)off; (void)ws_size; (void)n_in; (void)out_size;

  hipMemsetAsync(deg, 0, (size_t)N * 2 * 4, stream);

  const int NBD = (ET + 255) / 256;
  const int P = (N + 255) / 256;  // scan_final2 requires P <= 256 (N <= 65536): holds for N=50000

  prep_kernel<<<NB_W1 + NB_W2 + NBD, 256, 0, stream>>>(W1, W1b, W2, W2b, ei, E, N, deg);
  scan_block_sums<<<P, 256, 0, stream>>>(deg, part, N);
  scan_final2<<<P, 256, 0, stream>>>(deg, part, row_ptr, N);
  scatter_kernel<<<NBD, 256, 0, stream>>>(ei, E, N, row_ptr, fill, col);

  const int NB4 = (N + 3) / 4;

  // ---- layer 1 ----
  gemm1_mfma<<<(N + 63) / 64, 256, 0, stream>>>(x, W1b, h1b, a_src1, a_dst1, as1, ad1, N);
  agg1_kernel<<<NB4, 256, 0, stream>>>(h1b, as1, ad1, row_ptr, col, b1, y1b, N);

  // ---- layer 2 ----
  gemm2_mfma<<<(N + 63) / 64, 256, 0, stream>>>(y1b, W2b, h2, a_src2, a_dst2, as2, ad2, N);
  agg2_kernel<<<NB4, 256, 0, stream>>>(h2, as2, ad2, row_ptr, col, b2, out, N);
}

// Round 2
// 490.697 us; speedup vs baseline: 1.1021x; 1.0656x over previous
//
#include <hip/hip_runtime.h>
#include <hip/hip_bf16.h>
#include <math.h>

constexpr int IN_C = 1024;
constexpr int HEADS = 4;
constexpr int F1 = 256;
constexpr int OUT_C = 64;
constexpr float NEG = 0.2f;

using bf16x8 = __attribute__((ext_vector_type(8))) short;
using f32x4 = __attribute__((ext_vector_type(4))) float;

__device__ __forceinline__ float leaky(float x) { return x > 0.f ? x : NEG * x; }

__device__ __forceinline__ unsigned short bf16bits(float v) {
  __hip_bfloat16 b = __float2bfloat16(v);
  return *reinterpret_cast<unsigned short*>(&b);
}
__device__ __forceinline__ float bf2f(unsigned short u) {
  union { unsigned u; float f; } c; c.u = (unsigned)u << 16; return c.f;
}

#define GLD_LDS16(g, l)                                                        \
  __builtin_amdgcn_global_load_lds(                                            \
      (const __attribute__((address_space(1))) void*)(g),                      \
      (__attribute__((address_space(3))) void*)(l), 16, 0, 0)

// ---------------- fused prep: cvt W1 -> bf16, cvt W2 -> bf16, degree count ----------------
// block-range dispatch: [0,1024) = W1, [1024,1088) = W2, rest = degree.
constexpr int NB_W1 = (F1 * IN_C) / 256;    // 1024 (exact)
constexpr int NB_W2 = (OUT_C * F1) / 256;   // 64 (exact)

__global__ __launch_bounds__(256) void prep_kernel(const float* __restrict__ W1,
                                                   unsigned short* __restrict__ W1b,
                                                   const float* __restrict__ W2,
                                                   unsigned short* __restrict__ W2b,
                                                   const int* __restrict__ ei, int E, int N,
                                                   int* __restrict__ deg) {
  int b = blockIdx.x;
  if (b < NB_W1) {
    int i = b * 256 + threadIdx.x;
    W1b[i] = bf16bits(W1[i]);
  } else if (b < NB_W1 + NB_W2) {
    int i = (b - NB_W1) * 256 + threadIdx.x;
    W2b[i] = bf16bits(W2[i]);
  } else {
    int e = (b - NB_W1 - NB_W2) * 256 + threadIdx.x;
    if (e < E + N) {
      int dst = (e < E) ? ei[E + e] : (e - E);
      atomicAdd(&deg[dst], 1);
    }
  }
}

// ------- GEMM1: Hb[M,256] = X*W1^T (bf16 MFMA) + fused alpha dot-products ---------
// 128-row x 256-col blocks, 512 threads (8 waves: rg = wave>>2 row-group, cg4 = wave&3
// col-group/head). LDS 51KB -> 3 blocks/CU = 6 waves/SIMD (was 2/SIMD) to hide the
// per-K-tile barrier drain. Scatter fused as trailing blocks (independent work).
constexpr int LDTA = 72;

__global__ __launch_bounds__(512, 4) void gemm1_mfma(const float* __restrict__ X,
                                                     const unsigned short* __restrict__ Wb,
                                                     unsigned short* __restrict__ Hb,
                                                     const float* __restrict__ a_src,
                                                     const float* __restrict__ a_dst,
                                                     float* __restrict__ as_out,
                                                     float* __restrict__ ad_out, int M, int MB,
                                                     const int* __restrict__ ei, int E, int N,
                                                     const int* __restrict__ row_ptr,
                                                     int* __restrict__ fill,
                                                     int* __restrict__ col) {
  __shared__ unsigned short As[128 * LDTA];
  __shared__ unsigned short Bs[256 * 64];
  const int tid = threadIdx.x;

  if (blockIdx.x >= MB) {
    // ---- fused scatter (CSR column fill) ----
    int e = (blockIdx.x - MB) * 512 + tid;
    int ET = E + N;
    if (e < ET) {
      int src, dst;
      if (e < E) { src = ei[e]; dst = ei[E + e]; }
      else       { src = e - E; dst = e - E; }
      int pos = row_ptr[dst] + atomicAdd(&fill[dst], 1);
      col[pos] = src;
    }
    return;
  }

  const int wave = tid >> 6;
  const int lane = tid & 63;
  const int m15 = lane & 15;
  const int q = lane >> 4;
  const int rg = wave >> 2;   // row-group: 0..1 (64 rows each)
  const int cg4 = wave & 3;   // col-group / head: 0..3 (64 cols each)
  const int bm = blockIdx.x * 128;

  f32x4 acc[4][4];
#pragma unroll
  for (int i = 0; i < 4; ++i)
#pragma unroll
    for (int j = 0; j < 4; ++j) acc[i][j] = (f32x4){0.f, 0.f, 0.f, 0.f};

  const int ar = tid >> 2;           // 0..127: A row within tile
  const int acg = (tid & 3) * 16;    // 16-col chunk within K-tile
  const int agr = (bm + ar < M) ? (bm + ar) : (M - 1);
  const float* aptr = X + (size_t)agr * IN_C + acg;

  for (int kt = 0; kt < IN_C; kt += 64) {
    // A global loads first (HBM, longest latency)
    float4 a0 = *(const float4*)(aptr + kt + 0);
    float4 a1 = *(const float4*)(aptr + kt + 4);
    float4 a2 = *(const float4*)(aptr + kt + 8);
    float4 a3 = *(const float4*)(aptr + kt + 12);
    // B staging (L2-resident after first touch): 2048 16B-slots / 512 threads = 4
#pragma unroll
    for (int p = 0; p < 4; ++p) {
      int s = p * 512 + tid;
      int r = s >> 3;
      int cb = s & 7;
      const unsigned short* g = Wb + (size_t)r * IN_C + kt + ((cb ^ (r & 7)) << 3);
      GLD_LDS16(g, &Bs[(p * 512 + wave * 64) * 8]);
    }
    union { uint4 u4[2]; __hip_bfloat162 h[8]; } pk;
    pk.h[0] = __float22bfloat162_rn(make_float2(a0.x, a0.y));
    pk.h[1] = __float22bfloat162_rn(make_float2(a0.z, a0.w));
    pk.h[2] = __float22bfloat162_rn(make_float2(a1.x, a1.y));
    pk.h[3] = __float22bfloat162_rn(make_float2(a1.z, a1.w));
    pk.h[4] = __float22bfloat162_rn(make_float2(a2.x, a2.y));
    pk.h[5] = __float22bfloat162_rn(make_float2(a2.z, a2.w));
    pk.h[6] = __float22bfloat162_rn(make_float2(a3.x, a3.y));
    pk.h[7] = __float22bfloat162_rn(make_float2(a3.z, a3.w));
    *(uint4*)&As[ar * LDTA + acg] = pk.u4[0];
    *(uint4*)&As[ar * LDTA + acg + 8] = pk.u4[1];
    __syncthreads();

#pragma unroll
    for (int k0 = 0; k0 < 64; k0 += 32) {
      bf16x8 af[4], bfr[4];
#pragma unroll
      for (int i = 0; i < 4; ++i)
        af[i] = *(const bf16x8*)&As[(rg * 64 + i * 16 + m15) * LDTA + k0 + q * 8];
#pragma unroll
      for (int j = 0; j < 4; ++j) {
        int rb = cg4 * 64 + j * 16 + m15;
        int cbp = ((k0 >> 3) + q) ^ (rb & 7);
        bfr[j] = *(const bf16x8*)&Bs[rb * 64 + cbp * 8];
      }
#pragma unroll
      for (int i = 0; i < 4; ++i)
#pragma unroll
        for (int j = 0; j < 4; ++j)
          acc[i][j] = __builtin_amdgcn_mfma_f32_16x16x32_bf16(af[i], bfr[j], acc[i][j], 0, 0, 0);
    }
    __syncthreads();
  }
  float asf[4], adf[4];
#pragma unroll
  for (int j = 0; j < 4; ++j) {
    asf[j] = a_src[cg4 * 64 + j * 16 + m15];
    adf[j] = a_dst[cg4 * 64 + j * 16 + m15];
  }
#pragma unroll
  for (int i = 0; i < 4; ++i) {
#pragma unroll
    for (int r = 0; r < 4; ++r) {
      int row = bm + rg * 64 + i * 16 + q * 4 + r;
      if (row < M) {
#pragma unroll
        for (int j = 0; j < 4; ++j)
          Hb[(size_t)row * F1 + cg4 * 64 + j * 16 + m15] = bf16bits(acc[i][j][r]);
      }
      float s = acc[i][0][r] * asf[0] + acc[i][1][r] * asf[1] +
                acc[i][2][r] * asf[2] + acc[i][3][r] * asf[3];
      float d = acc[i][0][r] * adf[0] + acc[i][1][r] * adf[1] +
                acc[i][2][r] * adf[2] + acc[i][3][r] * adf[3];
#pragma unroll
      for (int o = 1; o < 16; o <<= 1) {
        s += __shfl_xor(s, o, 64);
        d += __shfl_xor(d, o, 64);
      }
      if (m15 == 0 && row < M) {
        as_out[row * HEADS + cg4] = s;
        ad_out[row * HEADS + cg4] = d;
      }
    }
  }
}

// ------- GEMM2: H2[M,64] = Y(bf16)*W2^T (bf16 MFMA) + fused alpha -----------------
__global__ __launch_bounds__(256, 4) void gemm2_mfma(const unsigned short* __restrict__ Y,
                                                     const unsigned short* __restrict__ W2b,
                                                     float* __restrict__ H2,
                                                     const float* __restrict__ a_src,
                                                     const float* __restrict__ a_dst,
                                                     float* __restrict__ as_out,
                                                     float* __restrict__ ad_out, int M) {
  __shared__ unsigned short As[64 * 64];
  __shared__ unsigned short Bs[64 * 64];
  const int tid = threadIdx.x;
  const int wave = tid >> 6;
  const int lane = tid & 63;
  const int m15 = lane & 15;
  const int q = lane >> 4;
  const int bm = blockIdx.x * 64;

  f32x4 acc[4];
#pragma unroll
  for (int j = 0; j < 4; ++j) acc[j] = (f32x4){0.f, 0.f, 0.f, 0.f};

  for (int kt = 0; kt < F1; kt += 64) {
#pragma unroll
    for (int p = 0; p < 2; ++p) {
      int s = p * 256 + tid;
      int r = s >> 3;
      int cb = s & 7;
      int colo = (cb ^ (r & 7)) << 3;
      int gr = (bm + r < M) ? (bm + r) : (M - 1);
      GLD_LDS16(Y + (size_t)gr * F1 + kt + colo, &As[(p * 256 + wave * 64) * 8]);
      GLD_LDS16(W2b + (size_t)r * F1 + kt + colo, &Bs[(p * 256 + wave * 64) * 8]);
    }
    __syncthreads();
#pragma unroll
    for (int k0 = 0; k0 < 64; k0 += 32) {
      int ra = wave * 16 + m15;
      bf16x8 af = *(const bf16x8*)&As[ra * 64 + ((((k0 >> 3) + q) ^ (ra & 7)) << 3)];
      bf16x8 bfr[4];
#pragma unroll
      for (int j = 0; j < 4; ++j) {
        int rb = j * 16 + m15;
        bfr[j] = *(const bf16x8*)&Bs[rb * 64 + ((((k0 >> 3) + q) ^ (rb & 7)) << 3)];
      }
#pragma unroll
      for (int j = 0; j < 4; ++j)
        acc[j] = __builtin_amdgcn_mfma_f32_16x16x32_bf16(af, bfr[j], acc[j], 0, 0, 0);
    }
    __syncthreads();
  }
  float asf[4], adf[4];
#pragma unroll
  for (int j = 0; j < 4; ++j) {
    asf[j] = a_src[j * 16 + m15];
    adf[j] = a_dst[j * 16 + m15];
  }
#pragma unroll
  for (int r = 0; r < 4; ++r) {
    int row = bm + wave * 16 + q * 4 + r;
    if (row < M) {
#pragma unroll
      for (int j = 0; j < 4; ++j) H2[(size_t)row * OUT_C + j * 16 + m15] = acc[j][r];
    }
    float s = acc[0][r] * asf[0] + acc[1][r] * asf[1] + acc[2][r] * asf[2] + acc[3][r] * asf[3];
    float d = acc[0][r] * adf[0] + acc[1][r] * adf[1] + acc[2][r] * adf[2] + acc[3][r] * adf[3];
#pragma unroll
    for (int o = 1; o < 16; o <<= 1) {
      s += __shfl_xor(s, o, 64);
      d += __shfl_xor(d, o, 64);
    }
    if (m15 == 0 && row < M) {
      as_out[row] = s;
      ad_out[row] = d;
    }
  }
}

// ---------------- CSR build ----------------
__global__ __launch_bounds__(256) void scan_block_sums(const int* __restrict__ deg,
                                                       int* __restrict__ part, int n) {
  __shared__ int sm[256];
  int t = threadIdx.x;
  int i = blockIdx.x * 256 + t;
  sm[t] = (i < n) ? deg[i] : 0;
  __syncthreads();
  for (int off = 128; off > 0; off >>= 1) {
    if (t < off) sm[t] += sm[t + off];
    __syncthreads();
  }
  if (t == 0) part[blockIdx.x] = sm[0];
}

// final scan: each block computes its own exclusive base from raw block sums
// (P <= 256 partials -> one wave-butterfly + LDS combine)
__global__ __launch_bounds__(256) void scan_final2(const int* __restrict__ deg,
                                                   const int* __restrict__ part,
                                                   int* __restrict__ row_ptr, int n) {
  __shared__ int sm[256];
  __shared__ int wsum[4];
  int t = threadIdx.x;
  int i = blockIdx.x * 256 + t;
  sm[t] = (i < n) ? deg[i] : 0;
  // exclusive base = sum of part[0..blockIdx.x-1]
  int pv = (t < blockIdx.x) ? part[t] : 0;
#pragma unroll
  for (int o = 1; o < 64; o <<= 1) pv += __shfl_xor(pv, o, 64);
  if ((t & 63) == 0) wsum[t >> 6] = pv;
  __syncthreads();
  for (int off = 1; off < 256; off <<= 1) {
    int u = (t >= off) ? sm[t - off] : 0;
    __syncthreads();
    sm[t] += u;
    __syncthreads();
  }
  int base = wsum[0] + wsum[1] + wsum[2] + wsum[3];
  if (i < n) row_ptr[i + 1] = base + sm[t];
  if (i == 0) row_ptr[0] = 0;
}

// ------- layer-1 aggregate: wave/dst, FOUR edges in flight per 32-lane half --------
// lane&31 = channel-group (8 ch, uint4), lane>>5 = edge parity; head = (lane&31)>>3.
__global__ __launch_bounds__(256) void agg1_kernel(const unsigned short* __restrict__ hb,
                                                   const float* __restrict__ as,
                                                   const float* __restrict__ ad,
                                                   const int* __restrict__ row_ptr,
                                                   const int* __restrict__ col,
                                                   const float* __restrict__ bias,
                                                   unsigned short* __restrict__ yb, int N) {
  int dst = (blockIdx.x * blockDim.x + threadIdx.x) >> 6;
  int lane = threadIdx.x & 63;
  if (dst >= N) return;
  const int s0 = row_ptr[dst], s1 = row_ptr[dst + 1];
  const int par = lane >> 5;
  const int cg = lane & 31;
  const int hh = cg >> 3;
  const float adl = ad[dst * 4 + hh];
  float acc[8];
#pragma unroll
  for (int k = 0; k < 8; ++k) acc[k] = 0.f;
  float den = 0.f;

  int i = s0 + par;
  for (; i + 6 < s1; i += 8) {  // 4 edges per parity per iter -> 8 rows in flight
    int sA = col[i], sB = col[i + 2], sC = col[i + 4], sD = col[i + 6];
    float wA = __expf(leaky(as[sA * 4 + hh] + adl));
    float wB = __expf(leaky(as[sB * 4 + hh] + adl));
    float wC = __expf(leaky(as[sC * 4 + hh] + adl));
    float wD = __expf(leaky(as[sD * 4 + hh] + adl));
    uint4 hA = *(const uint4*)(hb + (size_t)sA * F1 + cg * 8);
    uint4 hB = *(const uint4*)(hb + (size_t)sB * F1 + cg * 8);
    uint4 hC = *(const uint4*)(hb + (size_t)sC * F1 + cg * 8);
    uint4 hD = *(const uint4*)(hb + (size_t)sD * F1 + cg * 8);
    den += (wA + wB) + (wC + wD);
    const unsigned short* pa = (const unsigned short*)&hA;
    const unsigned short* pb = (const unsigned short*)&hB;
    const unsigned short* pc = (const unsigned short*)&hC;
    const unsigned short* pd = (const unsigned short*)&hD;
#pragma unroll
    for (int k = 0; k < 8; ++k) {
      acc[k] = fmaf(wA, bf2f(pa[k]), acc[k]);
      acc[k] = fmaf(wB, bf2f(pb[k]), acc[k]);
      acc[k] = fmaf(wC, bf2f(pc[k]), acc[k]);
      acc[k] = fmaf(wD, bf2f(pd[k]), acc[k]);
    }
  }
  for (; i + 2 < s1; i += 4) {  // 2 edges per parity
    int sA = col[i], sB = col[i + 2];
    float wA = __expf(leaky(as[sA * 4 + hh] + adl));
    float wB = __expf(leaky(as[sB * 4 + hh] + adl));
    uint4 hA = *(const uint4*)(hb + (size_t)sA * F1 + cg * 8);
    uint4 hB = *(const uint4*)(hb + (size_t)sB * F1 + cg * 8);
    den += wA + wB;
    const unsigned short* pa = (const unsigned short*)&hA;
    const unsigned short* pb = (const unsigned short*)&hB;
#pragma unroll
    for (int k = 0; k < 8; ++k) {
      acc[k] = fmaf(wA, bf2f(pa[k]), acc[k]);
      acc[k] = fmaf(wB, bf2f(pb[k]), acc[k]);
    }
  }
  for (; i < s1; i += 2) {
    int s = col[i];
    float w = __expf(leaky(as[s * 4 + hh] + adl));
    uint4 hv = *(const uint4*)(hb + (size_t)s * F1 + cg * 8);
    den += w;
    const unsigned short* p = (const unsigned short*)&hv;
#pragma unroll
    for (int k = 0; k < 8; ++k) acc[k] = fmaf(w, bf2f(p[k]), acc[k]);
  }
  // combine the two parities
  den += __shfl_xor(den, 32, 64);
#pragma unroll
  for (int k = 0; k < 8; ++k) acc[k] += __shfl_xor(acc[k], 32, 64);

  if (par == 0) {
    const float iv = 1.f / den;
    float4 b0 = *(const float4*)(bias + cg * 8);
    float4 b1 = *(const float4*)(bias + cg * 8 + 4);
    float bv[8] = {b0.x, b0.y, b0.z, b0.w, b1.x, b1.y, b1.z, b1.w};
    ushort4 o[2];
    unsigned short* po = (unsigned short*)o;
#pragma unroll
    for (int k = 0; k < 8; ++k) {
      float v = acc[k] * iv + bv[k];
      v = v > 0.f ? v : (__expf(v) - 1.f);
      po[k] = bf16bits(v);
    }
    *(uint4*)(yb + (size_t)dst * F1 + cg * 8) = *(uint4*)o;
  }
}

// ------- layer-2 aggregate: wave/dst, FOUR edges in flight per half ----------------
__global__ __launch_bounds__(256) void agg2_kernel(const float* __restrict__ h,
                                                   const float* __restrict__ as,
                                                   const float* __restrict__ ad,
                                                   const int* __restrict__ row_ptr,
                                                   const int* __restrict__ col,
                                                   const float* __restrict__ bias,
                                                   float* __restrict__ out, int N) {
  int dst = (blockIdx.x * blockDim.x + threadIdx.x) >> 6;
  int lane = threadIdx.x & 63;
  if (dst >= N) return;
  const int s0 = row_ptr[dst], s1 = row_ptr[dst + 1];
  const int par = lane >> 5;
  const int cg = lane & 31;
  const float adl = ad[dst];
  float a0 = 0.f, a1 = 0.f, den = 0.f;

  int i = s0 + par;
  for (; i + 6 < s1; i += 8) {
    int sA = col[i], sB = col[i + 2], sC = col[i + 4], sD = col[i + 6];
    float wA = __expf(leaky(as[sA] + adl));
    float wB = __expf(leaky(as[sB] + adl));
    float wC = __expf(leaky(as[sC] + adl));
    float wD = __expf(leaky(as[sD] + adl));
    float2 hA = *(const float2*)(h + (size_t)sA * OUT_C + cg * 2);
    float2 hB = *(const float2*)(h + (size_t)sB * OUT_C + cg * 2);
    float2 hC = *(const float2*)(h + (size_t)sC * OUT_C + cg * 2);
    float2 hD = *(const float2*)(h + (size_t)sD * OUT_C + cg * 2);
    den += (wA + wB) + (wC + wD);
    a0 = fmaf(wA, hA.x, a0); a1 = fmaf(wA, hA.y, a1);
    a0 = fmaf(wB, hB.x, a0); a1 = fmaf(wB, hB.y, a1);
    a0 = fmaf(wC, hC.x, a0); a1 = fmaf(wC, hC.y, a1);
    a0 = fmaf(wD, hD.x, a0); a1 = fmaf(wD, hD.y, a1);
  }
  for (; i + 2 < s1; i += 4) {
    int sA = col[i], sB = col[i + 2];
    float wA = __expf(leaky(as[sA] + adl));
    float wB = __expf(leaky(as[sB] + adl));
    float2 hA = *(const float2*)(h + (size_t)sA * OUT_C + cg * 2);
    float2 hB = *(const float2*)(h + (size_t)sB * OUT_C + cg * 2);
    den += wA + wB;
    a0 = fmaf(wA, hA.x, a0); a1 = fmaf(wA, hA.y, a1);
    a0 = fmaf(wB, hB.x, a0); a1 = fmaf(wB, hB.y, a1);
  }
  for (; i < s1; i += 2) {
    int s = col[i];
    float w = __expf(leaky(as[s] + adl));
    float2 hv = *(const float2*)(h + (size_t)s * OUT_C + cg * 2);
    den += w;
    a0 = fmaf(w, hv.x, a0); a1 = fmaf(w, hv.y, a1);
  }
  den += __shfl_xor(den, 32, 64);
  a0 += __shfl_xor(a0, 32, 64);
  a1 += __shfl_xor(a1, 32, 64);
  if (par == 0) {
    const float iv = 1.f / den;
    float2 bv = *(const float2*)(bias + cg * 2);
    float2 o = make_float2(a0 * iv + bv.x, a1 * iv + bv.y);
    *(float2*)(out + (size_t)dst * OUT_C + cg * 2) = o;
  }
}

extern "C" void kernel_launch(void* const* d_in, const int* in_sizes, int n_in,
                              void* d_out, int out_size, void* d_ws, size_t ws_size,
                              hipStream_t stream) {
  const float* x      = (const float*)d_in[0];
  const int*   ei     = (const int*)d_in[1];
  const float* W1     = (const float*)d_in[2];
  const float* a_src1 = (const float*)d_in[3];
  const float* a_dst1 = (const float*)d_in[4];
  const float* b1     = (const float*)d_in[5];
  const float* W2     = (const float*)d_in[6];
  const float* a_src2 = (const float*)d_in[7];
  const float* a_dst2 = (const float*)d_in[8];
  const float* b2     = (const float*)d_in[9];
  float* out = (float*)d_out;

  const int N = in_sizes[0] / IN_C;
  const int E = in_sizes[1] / 2;
  const int ET = E + N;

  char* ws = (char*)d_ws;
  size_t off = 0;
  auto alloc = [&](size_t bytes) -> void* {
    void* p = ws + off;
    off = (off + bytes + 255) & ~(size_t)255;
    return p;
  };
  unsigned short* h1b = (unsigned short*)alloc((size_t)N * F1 * 2);
  unsigned short* y1b = (unsigned short*)alloc((size_t)N * F1 * 2);
  float* h2      = (float*)alloc((size_t)N * OUT_C * 4);
  float* as1     = (float*)alloc((size_t)N * HEADS * 4);
  float* ad1     = (float*)alloc((size_t)N * HEADS * 4);
  float* as2     = (float*)alloc((size_t)N * 4);
  float* ad2     = (float*)alloc((size_t)N * 4);
  int*   deg     = (int*)alloc((size_t)N * 2 * 4);  // deg + fill, contiguous -> one memset
  int*   fill    = deg + N;
  int*   row_ptr = (int*)alloc((size_t)(N + 1) * 4);
  int*   col     = (int*)alloc((size_t)ET * 4);
  int*   part    = (int*)alloc(1024 * 4);
  unsigned short* W1b = (unsigned short*)alloc((size_t)F1 * IN_C * 2);
  unsigned short* W2b = (unsigned short*)alloc((size_t)OUT_C * F1 * 2);
  (void)off; (void)ws_size; (void)n_in; (void)out_size;

  hipMemsetAsync(deg, 0, (size_t)N * 2 * 4, stream);

  const int NBD = (ET + 255) / 256;
  const int P = (N + 255) / 256;  // scan_final2 requires P <= 256 (N <= 65536): holds for N=50000

  prep_kernel<<<NB_W1 + NB_W2 + NBD, 256, 0, stream>>>(W1, W1b, W2, W2b, ei, E, N, deg);
  scan_block_sums<<<P, 256, 0, stream>>>(deg, part, N);
  scan_final2<<<P, 256, 0, stream>>>(deg, part, row_ptr, N);

  const int NB4 = (N + 3) / 4;
  const int MB = (N + 127) / 128;
  const int SB = (ET + 511) / 512;

  // ---- layer 1 (gemm + fused scatter: independent work co-scheduled) ----
  gemm1_mfma<<<MB + SB, 512, 0, stream>>>(x, W1b, h1b, a_src1, a_dst1, as1, ad1, N, MB,
                                          ei, E, N, row_ptr, fill, col);
  agg1_kernel<<<NB4, 256, 0, stream>>>(h1b, as1, ad1, row_ptr, col, b1, y1b, N);

  // ---- layer 2 ----
  gemm2_mfma<<<(N + 63) / 64, 256, 0, stream>>>(y1b, W2b, h2, a_src2, a_dst2, as2, ad2, N);
  agg2_kernel<<<NB4, 256, 0, stream>>>(h2, as2, ad2, row_ptr, col, b2, out, N);
}